// Round 5
// baseline (8303.145 us; speedup 1.0000x reference)
//
#include <hip/hip_runtime.h>
#include <stdint.h>

#define BDIM 256
#define SEQL 128
#define IND 512
#define HID 512
#define KDIM 1024 // IND + HID
#define NBLK 256u
#define NPX 32u   // blocks per XCD-group (NBLK/8)

typedef __bf16 bf16x8 __attribute__((ext_vector_type(8)));
typedef float floatx4 __attribute__((ext_vector_type(4)));

__device__ __forceinline__ float sigm(float x) { return 1.0f / (1.0f + __expf(-x)); }

// bf16 RNE split helpers (finite data only)
__device__ __forceinline__ ushort f2bf(float v) {
  uint32_t x = __builtin_bit_cast(uint32_t, v);
  x += 0x7fffu + ((x >> 16) & 1u);
  return (ushort)(x >> 16);
}
__device__ __forceinline__ float bf2f(ushort u) {
  return __builtin_bit_cast(float, ((uint32_t)u) << 16);
}

struct AttnS { float sc[HID]; float sl[SEQL]; float sxi[2][HID]; };
struct GateS { ushort sA[2][64][72]; ushort sW[2][64][72]; };
union SU { AttnS a; GateS g; };

// Two-level tree barrier. Flat barrier (R3): 256 cross-die RMWs + 255 spinners
// on ONE cache line -> ~25us/barrier (polls starve arrivals at the owning L2
// bank). Tree: 32 arrivals per XCD-group line (8 lines), 8 arrivals at root,
// spin traffic partitioned 8-ways. Ordering identical to R3: RELEASE on
// arrival (flush L2), RELAXED spin (no per-poll invalidate), one ACQUIRE after
// exit (single invalidate per block).
// Deadlock audit: group cnt resets before root promotion; next-round arrivals
// gated by gen bump (after root); root round n+1 gated per-group by round-n
// rep exit; rgen monotonic -> stale spinners always exit.
// bar layout (uint idx): xcnt[g]=g*16, xgen[g]=128+g*16, rcnt=256, rgen=272.
__device__ __forceinline__ void gbar(unsigned* bar, int blk) {
  __syncthreads();  // per-wave vmcnt(0): stores reach this XCD's L2
  if (threadIdx.x == 0) {
    int g = blk & 7;
    unsigned* cnt  = bar + g * 16;
    unsigned* gen  = bar + 128 + g * 16;
    unsigned* rcnt = bar + 256;
    unsigned* rgen = bar + 272;
    unsigned g0 = __hip_atomic_load(gen, __ATOMIC_RELAXED, __HIP_MEMORY_SCOPE_AGENT);
    unsigned a = __hip_atomic_fetch_add(cnt, 1u, __ATOMIC_RELEASE, __HIP_MEMORY_SCOPE_AGENT);
    if (a == NPX - 1u) {  // group rep: promote to root
      __hip_atomic_store(cnt, 0u, __ATOMIC_RELAXED, __HIP_MEMORY_SCOPE_AGENT);
      unsigned r0 = __hip_atomic_load(rgen, __ATOMIC_RELAXED, __HIP_MEMORY_SCOPE_AGENT);
      unsigned ra = __hip_atomic_fetch_add(rcnt, 1u, __ATOMIC_ACQ_REL, __HIP_MEMORY_SCOPE_AGENT);
      if (ra == 7u) {
        __hip_atomic_store(rcnt, 0u, __ATOMIC_RELAXED, __HIP_MEMORY_SCOPE_AGENT);
        __hip_atomic_fetch_add(rgen, 1u, __ATOMIC_ACQ_REL, __HIP_MEMORY_SCOPE_AGENT);
      } else {
        while (__hip_atomic_load(rgen, __ATOMIC_RELAXED, __HIP_MEMORY_SCOPE_AGENT) == r0)
          __builtin_amdgcn_s_sleep(4);
        (void)__hip_atomic_load(rgen, __ATOMIC_ACQUIRE, __HIP_MEMORY_SCOPE_AGENT);
      }
      __hip_atomic_fetch_add(gen, 1u, __ATOMIC_ACQ_REL, __HIP_MEMORY_SCOPE_AGENT);
    } else {
      while (__hip_atomic_load(gen, __ATOMIC_RELAXED, __HIP_MEMORY_SCOPE_AGENT) == g0)
        __builtin_amdgcn_s_sleep(12);
      (void)__hip_atomic_load(gen, __ATOMIC_ACQUIRE, __HIP_MEMORY_SCOPE_AGENT);
    }
  }
  __syncthreads();
}

__global__ __launch_bounds__(256, 2) void k_persist(
    const float* __restrict__ x, const float* __restrict__ W_ih,
    const float* __restrict__ W_hh, const float* __restrict__ b_ih,
    const float* __restrict__ b_hh, const float* __restrict__ Wa,
    const float* __restrict__ ba, float* __restrict__ out,
    float* __restrict__ c, float* __restrict__ bias,
    ushort* __restrict__ Whi, ushort* __restrict__ Wlo,
    ushort* __restrict__ A0hi, ushort* __restrict__ A0lo,
    ushort* __restrict__ A1hi, ushort* __restrict__ A1lo,
    unsigned* bar) {
  __shared__ SU su;
  int blk = blockIdx.x;
  int tid = threadIdx.x;

  // ---- prologue A: W -> bf16 hi/lo [4H][IN|HID]; combined bias (8 rows/blk) ----
  for (int r = 0; r < 8; ++r) {
    int row = blk * 8 + r;
    if (tid == 0) bias[row] = b_ih[row] + b_hh[row];
    for (int k = tid; k < KDIM; k += 256) {
      float w = (k < IND) ? W_ih[(size_t)row * IND + k] : W_hh[(size_t)row * HID + (k - IND)];
      ushort hi = f2bf(w);
      Whi[(size_t)row * KDIM + k] = hi;
      Wlo[(size_t)row * KDIM + k] = f2bf(w - bf2f(hi));
    }
  }
  // ---- prologue B: init h0,c0 for batch blk (gates = bias) ----
  {
    int b = blk;
    for (int j = tid; j < HID; j += 256) {
      float bi = b_ih[j] + b_hh[j];
      float bg = b_ih[2 * HID + j] + b_hh[2 * HID + j];
      float bo = b_ih[3 * HID + j] + b_hh[3 * HID + j];
      float c0 = sigm(bi) * tanhf(bg);
      float h0 = sigm(bo) * tanhf(c0);
      c[b * HID + j] = c0;
      ushort hi = f2bf(h0);
      A0hi[(size_t)b * KDIM + IND + j] = hi;
      A0lo[(size_t)b * KDIM + IND + j] = f2bf(h0 - bf2f(hi));
    }
  }
  gbar(bar, blk);

  for (int t = 0; t < SEQL; ++t) {
    ushort* Rhi = (t & 1) ? A1hi : A0hi;
    ushort* Rlo = (t & 1) ? A1lo : A0lo;
    ushort* Dhi = (t & 1) ? A0hi : A1hi;
    ushort* Dlo = (t & 1) ? A0lo : A1lo;

    // ================= ATTN phase: block = batch blk =================
    {
      int b = blk;
      float* sc = su.a.sc;
      float* sl = su.a.sl;
      auto& sxi = su.a.sxi;
      sc[tid] = c[b * HID + tid];
      sc[tid + 256] = c[b * HID + tid + 256];
      __syncthreads();
      int wave = tid >> 6, lane = tid & 63;
      for (int si = 0; si < 32; ++si) {
        int s = wave * 32 + si;
        const float* wr = Wa + s * HID;
        float acc = 0.f;
#pragma unroll
        for (int it = 0; it < 8; ++it) {
          int k = lane + it * 64;
          acc += sc[k] * wr[k];
        }
#pragma unroll
        for (int off = 32; off > 0; off >>= 1) acc += __shfl_down(acc, off);
        if (lane == 0) sl[s] = acc + ba[s];
      }
      __syncthreads();
      if (tid < 64) {
        float v0 = sl[tid], v1 = sl[tid + 64];
        float m = fmaxf(v0, v1);
#pragma unroll
        for (int off = 32; off > 0; off >>= 1) m = fmaxf(m, __shfl_xor(m, off));
        float e0 = __expf(v0 - m), e1 = __expf(v1 - m);
        float s2 = e0 + e1;
#pragma unroll
        for (int off = 32; off > 0; off >>= 1) s2 += __shfl_xor(s2, off);
        float inv = 1.f / s2;
        sl[tid] = e0 * inv; sl[tid + 64] = e1 * inv;
      }
      __syncthreads();
      int cix = tid & 127;
      int ph = tid >> 7;
      const float* xrow = x + (size_t)b * SEQL * IND + (size_t)ph * 64 * IND;
      float4 a4 = {0.f, 0.f, 0.f, 0.f};
#pragma unroll 4
      for (int s = 0; s < 64; ++s) {
        float w = sl[ph * 64 + s];
        float4 v = *(const float4*)(xrow + s * IND + 4 * cix);
        a4.x += w * v.x; a4.y += w * v.y; a4.z += w * v.z; a4.w += w * v.w;
      }
      *(float4*)(&sxi[ph][4 * cix]) = a4;
      __syncthreads();
      float rx = sxi[0][2 * tid] + sxi[1][2 * tid];
      float ry = sxi[0][2 * tid + 1] + sxi[1][2 * tid + 1];
      ushort hx = f2bf(rx), hy = f2bf(ry);
      uint hp = (uint)hx | ((uint)hy << 16);
      uint lp = (uint)f2bf(rx - bf2f(hx)) | ((uint)f2bf(ry - bf2f(hy)) << 16);
      *(uint*)(Rhi + (size_t)b * KDIM + 2 * tid) = hp;
      *(uint*)(Rlo + (size_t)b * KDIM + 2 * tid) = lp;
    }
    gbar(bar, blk);

    // ================= GATES phase: blocks 0..127 =================
    if (blk < 128) {
      int lb = (blk & 7) * 16 + (blk >> 3);
      int j0 = (lb >> 2) * 16;
      int b0 = (lb & 3) * 64;

      int srow = tid >> 2;
      int scol = (tid & 3) * 16;
      const ushort* gAhi = Rhi + (size_t)(b0 + srow) * KDIM + scol;
      const ushort* gAlo = Rlo + (size_t)(b0 + srow) * KDIM + scol;
      int wrow = (srow >> 4) * HID + j0 + (srow & 15);
      const ushort* gWhi = Whi + (size_t)wrow * KDIM + scol;
      const ushort* gWlo = Wlo + (size_t)wrow * KDIM + scol;

      floatx4 acc[4];
      acc[0] = acc[1] = acc[2] = acc[3] = (floatx4){0.f, 0.f, 0.f, 0.f};

      int lane = tid & 63, bh = tid >> 6;
      int ml = lane & 15;
      int koff = (lane >> 4) * 8;
      const ushort* pAh = &su.g.sA[0][bh * 16 + ml][0];
      const ushort* pAl = &su.g.sA[1][bh * 16 + ml][0];
      const ushort* pWh = &su.g.sW[0][ml][0];
      const ushort* pWl = &su.g.sW[1][ml][0];

      uint4 pah0, pah1, pal0, pal1, pwh0, pwh1, pwl0, pwl1;
      pah0 = *(const uint4*)(gAhi);     pah1 = *(const uint4*)(gAhi + 8);
      pal0 = *(const uint4*)(gAlo);     pal1 = *(const uint4*)(gAlo + 8);
      pwh0 = *(const uint4*)(gWhi);     pwh1 = *(const uint4*)(gWhi + 8);
      pwl0 = *(const uint4*)(gWlo);     pwl1 = *(const uint4*)(gWlo + 8);

      for (int k0 = 0; k0 < KDIM; k0 += 64) {
        *(uint4*)&su.g.sA[0][srow][scol] = pah0;  *(uint4*)&su.g.sA[0][srow][scol + 8] = pah1;
        *(uint4*)&su.g.sA[1][srow][scol] = pal0;  *(uint4*)&su.g.sA[1][srow][scol + 8] = pal1;
        *(uint4*)&su.g.sW[0][srow][scol] = pwh0;  *(uint4*)&su.g.sW[0][srow][scol + 8] = pwh1;
        *(uint4*)&su.g.sW[1][srow][scol] = pwl0;  *(uint4*)&su.g.sW[1][srow][scol + 8] = pwl1;
        __syncthreads();
        int kn = k0 + 64;
        if (kn < KDIM) {
          pah0 = *(const uint4*)(gAhi + kn);     pah1 = *(const uint4*)(gAhi + kn + 8);
          pal0 = *(const uint4*)(gAlo + kn);     pal1 = *(const uint4*)(gAlo + kn + 8);
          pwh0 = *(const uint4*)(gWhi + kn);     pwh1 = *(const uint4*)(gWhi + kn + 8);
          pwl0 = *(const uint4*)(gWlo + kn);     pwl1 = *(const uint4*)(gWlo + kn + 8);
        }
#pragma unroll
        for (int ks = 0; ks < 2; ++ks) {
          int kb = ks * 32 + koff;
          bf16x8 ah = *(const bf16x8*)(pAh + kb);
          bf16x8 al = *(const bf16x8*)(pAl + kb);
#pragma unroll
          for (int g = 0; g < 4; ++g) {
            bf16x8 wh = *(const bf16x8*)(pWh + g * 16 * 72 + kb);
            bf16x8 wl = *(const bf16x8*)(pWl + g * 16 * 72 + kb);
            acc[g] = __builtin_amdgcn_mfma_f32_16x16x32_bf16(ah, wh, acc[g], 0, 0, 0);
            acc[g] = __builtin_amdgcn_mfma_f32_16x16x32_bf16(ah, wl, acc[g], 0, 0, 0);
            acc[g] = __builtin_amdgcn_mfma_f32_16x16x32_bf16(al, wh, acc[g], 0, 0, 0);
          }
        }
        __syncthreads();
      }

      int jg = j0 + ml;
      int rbase = b0 + bh * 16 + (lane >> 4) * 4;
      float bi = bias[jg], bf = bias[HID + jg], bg = bias[2 * HID + jg], bo = bias[3 * HID + jg];
#pragma unroll
      for (int r = 0; r < 4; ++r) {
        int b = rbase + r;
        float ig = sigm(acc[0][r] + bi);
        float fg = sigm(acc[1][r] + bf);
        float gg = tanhf(acc[2][r] + bg);
        float og = sigm(acc[3][r] + bo);
        float co = c[b * HID + jg];
        float cn = fg * co + ig * gg;
        float hv = og * tanhf(cn);
        c[b * HID + jg] = cn;
        out[((size_t)b * SEQL + t) * HID + jg] = hv;
        ushort hi = f2bf(hv);
        Dhi[(size_t)b * KDIM + IND + jg] = hi;
        Dlo[(size_t)b * KDIM + IND + jg] = f2bf(hv - bf2f(hi));
      }
    }
    gbar(bar, blk);
  }
}

extern "C" void kernel_launch(void* const* d_in, const int* in_sizes, int n_in,
                              void* d_out, int out_size, void* d_ws, size_t ws_size,
                              hipStream_t stream) {
  (void)in_sizes; (void)n_in; (void)out_size; (void)ws_size;
  const float* x    = (const float*)d_in[0];
  const float* W_ih = (const float*)d_in[1];
  const float* W_hh = (const float*)d_in[2];
  const float* b_ih = (const float*)d_in[3];
  const float* b_hh = (const float*)d_in[4];
  const float* Wa   = (const float*)d_in[5];
  const float* ba   = (const float*)d_in[6];
  float* out = (float*)d_out;

  char* p = (char*)d_ws;
  auto carve = [&](size_t bytes) { char* r = p; p += (bytes + 255) & ~(size_t)255; return r; };
  unsigned* bar = (unsigned*)carve(2048);  // tree-barrier lines (64B spaced)
  float*  c    = (float*)carve((size_t)BDIM * HID * 4);
  float*  bias = (float*)carve((size_t)4 * HID * 4);
  ushort* Whi  = (ushort*)carve((size_t)4 * HID * KDIM * 2);
  ushort* Wlo  = (ushort*)carve((size_t)4 * HID * KDIM * 2);
  ushort* A0hi = (ushort*)carve((size_t)BDIM * KDIM * 2);
  ushort* A0lo = (ushort*)carve((size_t)BDIM * KDIM * 2);
  ushort* A1hi = (ushort*)carve((size_t)BDIM * KDIM * 2);
  ushort* A1lo = (ushort*)carve((size_t)BDIM * KDIM * 2);

  hipMemsetAsync(bar, 0, 2048, stream);
  k_persist<<<NBLK, 256, 0, stream>>>(x, W_ih, W_hh, b_ih, b_hh, Wa, ba, out,
                                      c, bias, Whi, Wlo, A0hi, A0lo, A1hi, A1lo,
                                      bar);
}

// Round 6
// 5442.841 us; speedup vs baseline: 1.5255x; 1.5255x over previous
//
#include <hip/hip_runtime.h>
#include <stdint.h>

#define BDIM 256
#define SEQL 128
#define IND 512
#define HID 512
#define KDIM 1024 // IND + HID

typedef __bf16 bf16x8 __attribute__((ext_vector_type(8)));
typedef float floatx4 __attribute__((ext_vector_type(4)));

__device__ __forceinline__ float sigm(float x) { return 1.0f / (1.0f + __expf(-x)); }

// bf16 RNE split helpers (finite data only)
__device__ __forceinline__ ushort f2bf(float v) {
  uint32_t x = __builtin_bit_cast(uint32_t, v);
  x += 0x7fffu + ((x >> 16) & 1u);
  return (ushort)(x >> 16);
}
__device__ __forceinline__ float bf2f(ushort u) {
  return __builtin_bit_cast(float, ((uint32_t)u) << 16);
}

// ---- one-time: W -> bf16 hi/lo in [4H][IN|HID] row-major; combined bias ----
__global__ __launch_bounds__(256) void k_wconv(
    const float* __restrict__ W_ih, const float* __restrict__ W_hh,
    const float* __restrict__ b_ih, const float* __restrict__ b_hh,
    ushort* __restrict__ Whi, ushort* __restrict__ Wlo, float* __restrict__ bias) {
  int row = blockIdx.x;  // 0..2047 (torch order: i,f,g,o blocks of HID)
  if (threadIdx.x == 0) bias[row] = b_ih[row] + b_hh[row];
  for (int k = threadIdx.x; k < KDIM; k += 256) {
    float w = (k < IND) ? W_ih[(size_t)row * IND + k] : W_hh[(size_t)row * HID + (k - IND)];
    ushort hi = f2bf(w);
    Whi[(size_t)row * KDIM + k] = hi;
    Wlo[(size_t)row * KDIM + k] = f2bf(w - bf2f(hi));
  }
}

// ---- init: h0,c0 from the zero-input zero-state cell (gates = bias) ----
__global__ void k_init(const float* __restrict__ b_ih, const float* __restrict__ b_hh,
                       float* __restrict__ c, ushort* __restrict__ Ahi, ushort* __restrict__ Alo) {
  int b = blockIdx.x;
  for (int j = threadIdx.x; j < HID; j += blockDim.x) {
    float bi = b_ih[j] + b_hh[j];
    float bg = b_ih[2 * HID + j] + b_hh[2 * HID + j];
    float bo = b_ih[3 * HID + j] + b_hh[3 * HID + j];
    float c0 = sigm(bi) * tanhf(bg);
    float h0 = sigm(bo) * tanhf(c0);
    c[b * HID + j] = c0;
    ushort hi = f2bf(h0);
    Ahi[(size_t)b * KDIM + IND + j] = hi;
    Alo[(size_t)b * KDIM + IND + j] = f2bf(h0 - bf2f(hi));
  }
}

// ---- per step: attention logits -> softmax -> xi (bf16 hi/lo into acts) ----
// ILP version: sc fragment hoisted to regs (loop-invariant), Wa as float4,
// unroll-4 logits rows (8 global loads in flight, 4 shfl chains interleaved),
// unroll-8 paired xi loop (16 loads in flight). At 1 wave/SIMD there is no
// TLP -- all latency hiding must come from ILP.
__global__ __launch_bounds__(256) void k_attn(const float* __restrict__ c, const float* __restrict__ Wa,
                                              const float* __restrict__ ba, const float* __restrict__ x,
                                              ushort* __restrict__ Ahi, ushort* __restrict__ Alo) {
  __shared__ float sc[HID];
  __shared__ float sl[SEQL];
  __shared__ float sxi[2][HID];
  int b = blockIdx.x, tid = threadIdx.x;
  sc[tid] = c[b * HID + tid];
  sc[tid + 256] = c[b * HID + tid + 256];
  __syncthreads();
  int wave = tid >> 6, lane = tid & 63;
  // lane's c-fragment: k in {4*lane..4*lane+3} u {256+4*lane..+3} (reordered
  // vs scalar version -- same terms, fp order change only)
  float4 c0 = *(const float4*)(&sc[lane * 4]);
  float4 c1 = *(const float4*)(&sc[lane * 4 + 256]);
#pragma unroll 4
  for (int si = 0; si < 32; ++si) {
    int s = wave * 32 + si;
    const float4* wr = (const float4*)(Wa + (size_t)s * HID);
    float4 w0 = wr[lane];
    float4 w1 = wr[lane + 64];
    float acc = c0.x * w0.x + c0.y * w0.y + c0.z * w0.z + c0.w * w0.w
              + c1.x * w1.x + c1.y * w1.y + c1.z * w1.z + c1.w * w1.w;
#pragma unroll
    for (int off = 32; off > 0; off >>= 1) acc += __shfl_down(acc, off);
    if (lane == 0) sl[s] = acc + ba[s];
  }
  __syncthreads();
  if (tid < 64) {
    float v0 = sl[tid], v1 = sl[tid + 64];
    float m = fmaxf(v0, v1);
#pragma unroll
    for (int off = 32; off > 0; off >>= 1) m = fmaxf(m, __shfl_xor(m, off));
    float e0 = __expf(v0 - m), e1 = __expf(v1 - m);
    float s2 = e0 + e1;
#pragma unroll
    for (int off = 32; off > 0; off >>= 1) s2 += __shfl_xor(s2, off);
    float inv = 1.f / s2;
    sl[tid] = e0 * inv; sl[tid + 64] = e1 * inv;
  }
  __syncthreads();
  // xi: float4 per thread, seq split into two halves across the block;
  // paired accumulators break the dependent FMA chain, unroll-8 pairs
  int cix = tid & 127;
  int ph = tid >> 7;
  const float* xrow = x + (size_t)b * SEQL * IND + (size_t)ph * 64 * IND;
  float4 aE = {0.f, 0.f, 0.f, 0.f}, aO = {0.f, 0.f, 0.f, 0.f};
#pragma unroll 8
  for (int s = 0; s < 64; s += 2) {
    float w0 = sl[ph * 64 + s];
    float w1 = sl[ph * 64 + s + 1];
    float4 v0 = *(const float4*)(xrow + (size_t)s * IND + 4 * cix);
    float4 v1 = *(const float4*)(xrow + (size_t)(s + 1) * IND + 4 * cix);
    aE.x += w0 * v0.x; aE.y += w0 * v0.y; aE.z += w0 * v0.z; aE.w += w0 * v0.w;
    aO.x += w1 * v1.x; aO.y += w1 * v1.y; aO.z += w1 * v1.z; aO.w += w1 * v1.w;
  }
  float4 a4 = {aE.x + aO.x, aE.y + aO.y, aE.z + aO.z, aE.w + aO.w};
  *(float4*)(&sxi[ph][4 * cix]) = a4;
  __syncthreads();
  float rx = sxi[0][2 * tid] + sxi[1][2 * tid];
  float ry = sxi[0][2 * tid + 1] + sxi[1][2 * tid + 1];
  ushort hx = f2bf(rx), hy = f2bf(ry);
  uint hp = (uint)hx | ((uint)hy << 16);
  uint lp = (uint)f2bf(rx - bf2f(hx)) | ((uint)f2bf(ry - bf2f(hy)) << 16);
  *(uint*)(Ahi + (size_t)b * KDIM + 2 * tid) = hp;
  *(uint*)(Alo + (size_t)b * KDIM + 2 * tid) = lp;
}

// ---- per step: 3xBF16-split MFMA GEMM gates = A @ W^T + fused cell update ----
// Double-buffered LDS: ONE __syncthreads per k-chunk (was 2), two register
// prefetch sets give the global loads a ~2-chunk in-flight window (covers
// ~900cy L3 latency; L2 is cold each step from the kernel-boundary flush).
#define LOADSET(R, KO) do { \
  R##0 = *(const uint4*)(gAhi + (KO));      R##1 = *(const uint4*)(gAhi + (KO) + 8);  \
  R##2 = *(const uint4*)(gAlo + (KO));      R##3 = *(const uint4*)(gAlo + (KO) + 8);  \
  R##4 = *(const uint4*)(gWhi + (KO));      R##5 = *(const uint4*)(gWhi + (KO) + 8);  \
  R##6 = *(const uint4*)(gWlo + (KO));      R##7 = *(const uint4*)(gWlo + (KO) + 8);  } while (0)
#define STORESET(BUF, R) do { \
  *(uint4*)&sA[BUF][0][srow][scol] = R##0;  *(uint4*)&sA[BUF][0][srow][scol + 8] = R##1; \
  *(uint4*)&sA[BUF][1][srow][scol] = R##2;  *(uint4*)&sA[BUF][1][srow][scol + 8] = R##3; \
  *(uint4*)&sW[BUF][0][srow][scol] = R##4;  *(uint4*)&sW[BUF][0][srow][scol + 8] = R##5; \
  *(uint4*)&sW[BUF][1][srow][scol] = R##6;  *(uint4*)&sW[BUF][1][srow][scol + 8] = R##7; } while (0)
#define COMPUTE(BUF) do { \
  _Pragma("unroll") for (int ks = 0; ks < 2; ++ks) { \
    int kb = ks * 32 + koff; \
    bf16x8 ah = *(const bf16x8*)(&sA[BUF][0][bh * 16 + ml][kb]); \
    bf16x8 al = *(const bf16x8*)(&sA[BUF][1][bh * 16 + ml][kb]); \
    _Pragma("unroll") for (int g = 0; g < 4; ++g) { \
      bf16x8 wh = *(const bf16x8*)(&sW[BUF][0][g * 16 + ml][kb]); \
      bf16x8 wl = *(const bf16x8*)(&sW[BUF][1][g * 16 + ml][kb]); \
      acc[g] = __builtin_amdgcn_mfma_f32_16x16x32_bf16(ah, wh, acc[g], 0, 0, 0); \
      acc[g] = __builtin_amdgcn_mfma_f32_16x16x32_bf16(ah, wl, acc[g], 0, 0, 0); \
      acc[g] = __builtin_amdgcn_mfma_f32_16x16x32_bf16(al, wh, acc[g], 0, 0, 0); } } } while (0)

__global__ __launch_bounds__(256) void k_gates(
    const ushort* __restrict__ Whi, const ushort* __restrict__ Wlo,
    const float* __restrict__ bias,
    const ushort* __restrict__ Ahi, const ushort* __restrict__ Alo,
    float* __restrict__ c, float* __restrict__ out,
    ushort* __restrict__ Dhi, ushort* __restrict__ Dlo, int tstep) {
  // chunked XCD decode: XCD n (=bid%8) gets j-tiles 4n..4n+3 for all 4 batch
  // tiles -> 1 MB W + 2 MB A per XCD L2 (R1-proven mapping).
  int bid = blockIdx.x;
  int lb = (bid & 7) * 16 + (bid >> 3);
  int j0 = (lb >> 2) * 16;   // hidden-j tile base (0..496)
  int b0 = (lb & 3) * 64;    // batch tile base (0..192)

  __shared__ __align__(16) ushort sA[2][2][64][72];  // [buf][hi/lo][batch][k]
  __shared__ __align__(16) ushort sW[2][2][64][72];  // [buf][hi/lo][g*16+jj][k]

  int tid = threadIdx.x;
  int srow = tid >> 2;
  int scol = (tid & 3) * 16;
  const ushort* gAhi = Ahi + (size_t)(b0 + srow) * KDIM + scol;
  const ushort* gAlo = Alo + (size_t)(b0 + srow) * KDIM + scol;
  int wrow = (srow >> 4) * HID + j0 + (srow & 15);  // global W row g*512+j
  const ushort* gWhi = Whi + (size_t)wrow * KDIM + scol;
  const ushort* gWlo = Wlo + (size_t)wrow * KDIM + scol;

  floatx4 acc[4];
  acc[0] = acc[1] = acc[2] = acc[3] = (floatx4){0.f, 0.f, 0.f, 0.f};

  int lane = tid & 63, bh = tid >> 6;
  int ml = lane & 15;
  int koff = (lane >> 4) * 8;

  uint4 A0, A1, A2, A3, A4, A5, A6, A7;  // even-chunk prefetch set
  uint4 B0, B1, B2, B3, B4, B5, B6, B7;  // odd-chunk prefetch set

  // prolog: chunks 0,1 staged; chunks 2,3 in flight
  LOADSET(A, 0);
  LOADSET(B, 64);
  STORESET(0, A);
  STORESET(1, B);
  LOADSET(A, 128);
  LOADSET(B, 192);
  __syncthreads();

  for (int k0 = 0; k0 < 16; k0 += 2) {
    COMPUTE(0);                                   // chunk k0 (even)
    __syncthreads();
    if (k0 + 2 < 16) {
      STORESET(0, A);                             // chunk k0+2
      if (k0 + 4 < 16) LOADSET(A, (k0 + 4) * 64); // issue chunk k0+4
    }
    COMPUTE(1);                                   // chunk k0+1 (odd)
    __syncthreads();
    if (k0 + 3 < 16) {
      STORESET(1, B);                             // chunk k0+3
      if (k0 + 5 < 16) LOADSET(B, (k0 + 5) * 64); // issue chunk k0+5
    }
  }

  // epilogue: lane owns 4 batches x 1 j, all 4 gates in-register
  int jg = j0 + ml;
  int rbase = b0 + bh * 16 + (lane >> 4) * 4;
  float bi = bias[jg], bf = bias[HID + jg], bg = bias[2 * HID + jg], bo = bias[3 * HID + jg];
#pragma unroll
  for (int r = 0; r < 4; ++r) {
    int b = rbase + r;
    float ig = sigm(acc[0][r] + bi);
    float fg = sigm(acc[1][r] + bf);
    float gg = tanhf(acc[2][r] + bg);
    float og = sigm(acc[3][r] + bo);
    float co = c[b * HID + jg];
    float cn = fg * co + ig * gg;
    float hv = og * tanhf(cn);
    c[b * HID + jg] = cn;
    out[((size_t)b * SEQL + tstep) * HID + jg] = hv;
    ushort hi = f2bf(hv);
    Dhi[(size_t)b * KDIM + IND + jg] = hi;
    Dlo[(size_t)b * KDIM + IND + jg] = f2bf(hv - bf2f(hi));
  }
}

extern "C" void kernel_launch(void* const* d_in, const int* in_sizes, int n_in,
                              void* d_out, int out_size, void* d_ws, size_t ws_size,
                              hipStream_t stream) {
  (void)in_sizes; (void)n_in; (void)out_size; (void)ws_size;
  const float* x    = (const float*)d_in[0];
  const float* W_ih = (const float*)d_in[1];
  const float* W_hh = (const float*)d_in[2];
  const float* b_ih = (const float*)d_in[3];
  const float* b_hh = (const float*)d_in[4];
  const float* Wa   = (const float*)d_in[5];
  const float* ba   = (const float*)d_in[6];
  float* out = (float*)d_out;

  // ws footprint: ~10.6 MiB
  char* p = (char*)d_ws;
  auto carve = [&](size_t bytes) { char* r = p; p += (bytes + 255) & ~(size_t)255; return r; };
  float*  c    = (float*)carve((size_t)BDIM * HID * 4);
  float*  bias = (float*)carve((size_t)4 * HID * 4);
  ushort* Whi  = (ushort*)carve((size_t)4 * HID * KDIM * 2);
  ushort* Wlo  = (ushort*)carve((size_t)4 * HID * KDIM * 2);
  ushort* A0hi = (ushort*)carve((size_t)BDIM * KDIM * 2);
  ushort* A0lo = (ushort*)carve((size_t)BDIM * KDIM * 2);
  ushort* A1hi = (ushort*)carve((size_t)BDIM * KDIM * 2);
  ushort* A1lo = (ushort*)carve((size_t)BDIM * KDIM * 2);

  k_wconv<<<4 * HID, 256, 0, stream>>>(W_ih, W_hh, b_ih, b_hh, Whi, Wlo, bias);
  k_init<<<BDIM, 256, 0, stream>>>(b_ih, b_hh, c, A0hi, A0lo);

  for (int t = 0; t < SEQL; ++t) {
    ushort* Rhi = (t & 1) ? A1hi : A0hi;
    ushort* Rlo = (t & 1) ? A1lo : A0lo;
    ushort* Dhi = (t & 1) ? A0hi : A1hi;
    ushort* Dlo = (t & 1) ? A0lo : A1lo;
    k_attn<<<BDIM, 256, 0, stream>>>(c, Wa, ba, x, Rhi, Rlo);
    k_gates<<<128, 256, 0, stream>>>(Whi, Wlo, bias, Rhi, Rlo, c, out, Dhi, Dlo, t);
  }
}